// Round 10
// baseline (390.737 us; speedup 1.0000x reference)
//
#include <hip/hip_runtime.h>
#include <hip/hip_bf16.h>

// HAN forward, del-branch only (add-branch _group output is unused in the reference).
// Inputs f32 / int32; output f32 [4096,256]. h and out_* stored bf16.
//
// R10: gemm_h2 rewritten around global_load_lds (guide "common mistake #1"):
//  - A staged f32 direct-to-LDS (width=16 DMA, no VGPR round-trip); cvt after ds_read.
//  - W pre-converted to bf16 (tiny cvt_w kernel); B staged bf16 via global_load_lds.
//  - TRIPLE buffer, raw `s_waitcnt vmcnt(6)` + `lgkmcnt(0); s_barrier` (no vmcnt(0)
//    drain: prefetch DMA stays in flight across the barrier, ~2 iters of slack).
//  - LDS tiles unpadded-contiguous (DMA requires it); frag reads are contiguous
//    1KB/wave -> conflict-free. BM=BN=128, bn-inner id order for L3 X-reuse.
//  - scan_two: int4-blocked (5 chunks, 3 barriers each).

typedef unsigned short u16;
typedef __attribute__((ext_vector_type(8))) __bf16 bf16x8;
typedef __attribute__((ext_vector_type(4))) float f32x4;
typedef const __attribute__((address_space(1))) unsigned int* gu32p;
typedef __attribute__((address_space(3))) unsigned int* su32p;

__device__ inline float bf2f(u16 u) {
    union { unsigned int i; float f; } c; c.i = ((unsigned int)u) << 16; return c.f;
}
__device__ inline u16 f2bf(float f) {  // round-to-nearest-even
    union { float f; unsigned int i; } c; c.f = f;
    return (u16)((c.i + 0x7fffu + ((c.i >> 16) & 1u)) >> 16);
}
__device__ inline bf16x8 cvt8(f32x4 a, f32x4 b) {
    bf16x8 r;
    r[0] = (__bf16)a[0]; r[1] = (__bf16)a[1]; r[2] = (__bf16)a[2]; r[3] = (__bf16)a[3];
    r[4] = (__bf16)b[0]; r[5] = (__bf16)b[1]; r[6] = (__bf16)b[2]; r[7] = (__bf16)b[3];
    return r;
}
__device__ inline float fast_tanh(float x) {
    x = fminf(9.f, fmaxf(-9.f, x));
    float t = __expf(2.f * x);
    return (t - 1.f) / (t + 1.f);
}

// ---------------- 0. W f32 -> bf16 (once, tiny) -------------------------------------
__global__ __launch_bounds__(256) void cvt_w(const float* __restrict__ W0, u16* __restrict__ wb0,
                                             const float* __restrict__ W1, u16* __restrict__ wb1) {
    int idx = blockIdx.x * 256 + threadIdx.x;   // grid 192: 24576 thr/array x 8 elems
    const int half = 96 * 256;
    const float* s; u16* d; int i;
    if (idx < half) { s = W0; d = wb0; i = idx; } else { s = W1; d = wb1; i = idx - half; }
    int e = i * 8;
    *(bf16x8*)(d + e) = cvt8(*(const f32x4*)(s + e), *(const f32x4*)(s + e + 4));
}

// ---------------- 1. h = X @ W^T + b, DMA-staged triple-buffered GEMM ---------------
// BM=BN=128 BK=32; 4 waves 2x2, wave = 64x64 = 4x4 frags = 16 MFMA/kstep.
// A tile: 128 rows x 32 f32 (16 KB) x3 bufs; B tile: 128 x 32 bf16 (8 KB) x3.
__global__ __launch_bounds__(256) void gemm_h2(const float* __restrict__ X0, const u16* __restrict__ Wb0,
                                               const float* __restrict__ b0, u16* __restrict__ H0,
                                               const float* __restrict__ X1, const u16* __restrict__ Wb1,
                                               const float* __restrict__ b1, u16* __restrict__ H1, int M) {
    __shared__ float Af[3][128 * 32];    // 48 KB
    __shared__ u16   Bb[3][128 * 32];    // 24 KB
    int id = blockIdx.x;
    int which = id >= 314;
    if (which) id -= 314;
    int bm = id >> 1, bn = id & 1;
    const float* X = which ? X1 : X0;
    const u16* Wb = which ? Wb1 : Wb0;
    const float* bias = which ? b1 : b0;
    u16* H = which ? H1 : H0;

    int tid = threadIdx.x;
    int w = tid >> 6, lane = tid & 63;
    int wm = w & 1, wn = w >> 1;
    int row16 = lane & 15, quad = lane >> 4;

// issue tile kt into buffer b: 4 A-DMAs + 2 B-DMAs per wave (vmcnt +6)
#define ISSUE(kt, b) { \
    int kA = (kt) * 32; \
    _Pragma("unroll") \
    for (int j = 0; j < 4; ++j) { \
        int rloc = (w * 4 + j) * 8 + (lane >> 3); \
        int rg = bm * 128 + rloc; if (rg > M - 1) rg = M - 1; \
        const float* gp = X + (size_t)rg * 768 + kA + (lane & 7) * 4; \
        float* lp = Af[b] + (w * 4 + j) * 256; \
        __builtin_amdgcn_global_load_lds((gu32p)(const void*)gp, (su32p)(void*)lp, 16, 0, 0); \
    } \
    _Pragma("unroll") \
    for (int j = 0; j < 2; ++j) { \
        int rw = (w * 2 + j) * 16 + (lane >> 2); \
        const u16* gp = Wb + (size_t)(bn * 128 + rw) * 768 + kA + (lane & 3) * 8; \
        u16* lp = Bb[b] + (w * 2 + j) * 512; \
        __builtin_amdgcn_global_load_lds((gu32p)(const void*)gp, (su32p)(void*)lp, 16, 0, 0); \
    } }

    ISSUE(0, 0)
    ISSUE(1, 1)

    f32x4 acc[4][4] = {};
#pragma unroll
    for (int ks = 0; ks < 24; ++ks) {
        int cur = ks % 3;
        if (ks < 23) { asm volatile("s_waitcnt vmcnt(6)" ::: "memory"); }
        else         { asm volatile("s_waitcnt vmcnt(0)" ::: "memory"); }
        asm volatile("s_waitcnt lgkmcnt(0)\ns_barrier" ::: "memory");
        if (ks + 2 < 24) { int nb = (ks + 2) % 3; ISSUE(ks + 2, nb) }
        bf16x8 af[4], bv[4];
#pragma unroll
        for (int mi = 0; mi < 4; ++mi) {
            const float* ap = Af[cur] + (wm * 64 + mi * 16 + row16) * 32 + quad * 8;
            af[mi] = cvt8(*(const f32x4*)ap, *(const f32x4*)(ap + 4));
        }
#pragma unroll
        for (int ni = 0; ni < 4; ++ni)
            bv[ni] = *(const bf16x8*)(Bb[cur] + (wn * 64 + ni * 16 + row16) * 32 + quad * 8);
#pragma unroll
        for (int mi = 0; mi < 4; ++mi)
#pragma unroll
            for (int ni = 0; ni < 4; ++ni)
                acc[mi][ni] = __builtin_amdgcn_mfma_f32_16x16x32_bf16(af[mi], bv[ni], acc[mi][ni], 0, 0, 0);
    }
#undef ISSUE

    // ---- coalesced epilogue via LDS (reuse Af: 128 x 136 u16 = 34.8 KB) ----
    __syncthreads();
    u16* eps = (u16*)Af;
    const int SE2 = 136;
#pragma unroll
    for (int ni = 0; ni < 4; ++ni) {
        int lcol = wn * 64 + ni * 16 + row16;
        float bvv = bias[bn * 128 + lcol];
#pragma unroll
        for (int mi = 0; mi < 4; ++mi)
#pragma unroll
            for (int r = 0; r < 4; ++r)
                eps[(wm * 64 + mi * 16 + quad * 4 + r) * SE2 + lcol] = f2bf(acc[mi][ni][r] + bvv);
    }
    __syncthreads();
    int mlim = M - bm * 128;
#pragma unroll
    for (int p = 0; p < 8; ++p) {
        int row = p * 16 + (tid >> 4);
        if (row < mlim) {
            int chunk = (tid & 15) * 8;
            uint4 v = *(const uint4*)(eps + row * SE2 + chunk);
            *(uint4*)(H + (size_t)(bm * 128 + row) * 256 + bn * 128 + chunk) = v;
        }
    }
}

// ---------------- 2. per-(node,head) attention scores (h bf16) ----------------------
__global__ __launch_bounds__(256) void node_scores(const u16* __restrict__ ha, const u16* __restrict__ hd,
                                                   const float* __restrict__ w_ads, const float* __restrict__ w_add,
                                                   const float* __restrict__ w_dds, const float* __restrict__ w_ddd,
                                                   float* __restrict__ as_ad, float* __restrict__ ad_ad,
                                                   float* __restrict__ as_dd, float* __restrict__ ad_dd, int N) {
    int gid = blockIdx.x * 256 + threadIdx.x;
    int n = gid >> 6;
    if (n >= N) return;
    int lane = gid & 63;
    int f = lane * 4;
    ushort4 av = *(const ushort4*)(ha + (size_t)n * 256 + f);
    ushort4 dv = *(const ushort4*)(hd + (size_t)n * 256 + f);
    float4 w1 = *(const float4*)(w_ads + f);
    float4 w2 = *(const float4*)(w_add + f);
    float4 w3 = *(const float4*)(w_dds + f);
    float4 w4 = *(const float4*)(w_ddd + f);
    float a0 = bf2f(av.x), a1 = bf2f(av.y), a2 = bf2f(av.z), a3 = bf2f(av.w);
    float d0 = bf2f(dv.x), d1 = bf2f(dv.y), d2 = bf2f(dv.z), d3 = bf2f(dv.w);
    float p1 = a0 * w1.x + a1 * w1.y + a2 * w1.z + a3 * w1.w;
    float p2 = d0 * w2.x + d1 * w2.y + d2 * w2.z + d3 * w2.w;
    float p3 = d0 * w3.x + d1 * w3.y + d2 * w3.z + d3 * w3.w;
    float p4 = d0 * w4.x + d1 * w4.y + d2 * w4.z + d3 * w4.w;
#pragma unroll
    for (int off = 16; off >= 1; off >>= 1) {
        p1 += __shfl_down(p1, off, 32);
        p2 += __shfl_down(p2, off, 32);
        p3 += __shfl_down(p3, off, 32);
        p4 += __shfl_down(p4, off, 32);
    }
    if ((lane & 31) == 0) {
        int h = lane >> 5;
        as_ad[n * 2 + h] = p1;
        ad_ad[n * 2 + h] = p2;
        as_dd[n * 2 + h] = p3;
        ad_dd[n * 2 + h] = p4;
    }
}

// ---------------- 3a. degree histogram, both edge sets ------------------------------
__global__ __launch_bounds__(256) void count_edges2(const int* __restrict__ eiA, int* __restrict__ cntA,
                                                    const int* __restrict__ eiB, int* __restrict__ cntB, int E) {
    int idx = blockIdx.x * 256 + threadIdx.x;
    int which = idx >= E;
    int e = idx - (which ? E : 0);
    if (e >= E) return;
    const int* ei = which ? eiB : eiA;
    int* cnt = which ? cntB : cntA;
    atomicAdd(&cnt[ei[E + e]], 1);
}

// ---------------- 3b. exclusive scan, int4-blocked (5 chunks x 3 barriers) ----------
__global__ __launch_bounds__(1024) void scan_two(const int* __restrict__ cntA, int* __restrict__ offA,
                                                 const int* __restrict__ cntB, int* __restrict__ offB, int n) {
    const int* cnt = blockIdx.x ? cntB : cntA;
    int* off = blockIdx.x ? offB : offA;
    __shared__ int wsum[16];
    __shared__ int woff[16];
    __shared__ int tot_s;
    __shared__ int carry_s;
    int tid = threadIdx.x, wid = tid >> 6, lane = tid & 63;
    if (tid == 0) carry_s = 0;
    __syncthreads();
    for (int base = 0; base < n; base += 4096) {
        int i = base + tid * 4;
        int v0 = (i + 0 < n) ? cnt[i + 0] : 0;
        int v1 = (i + 1 < n) ? cnt[i + 1] : 0;
        int v2 = (i + 2 < n) ? cnt[i + 2] : 0;
        int v3 = (i + 3 < n) ? cnt[i + 3] : 0;
        int s0 = v0, s1 = s0 + v1, s2 = s1 + v2, s3 = s2 + v3;
        int x = s3;
#pragma unroll
        for (int d = 1; d < 64; d <<= 1) {
            int t = __shfl_up(x, d, 64);
            if (lane >= d) x += t;
        }
        if (lane == 63) wsum[wid] = x;
        __syncthreads();
        if (wid == 0) {
            int s = (lane < 16) ? wsum[lane] : 0;
#pragma unroll
            for (int d = 1; d < 16; d <<= 1) {
                int t = __shfl_up(s, d, 64);
                if (lane >= d) s += t;
            }
            if (lane < 16) woff[lane] = s - wsum[lane];
            if (lane == 15) tot_s = s;
        }
        __syncthreads();
        int basev = carry_s + woff[wid] + (x - s3);   // exclusive base for this thread
        if (i + 0 < n) off[i + 0] = basev;
        if (i + 1 < n) off[i + 1] = basev + s0;
        if (i + 2 < n) off[i + 2] = basev + s1;
        if (i + 3 < n) off[i + 3] = basev + s2;
        __syncthreads();
        if (tid == 0) carry_s += tot_s;
    }
    __syncthreads();
    if (tid == 0) off[n] = carry_s;
}

// ---------------- 3c. fill CSR src lists, both edge sets ----------------------------
__global__ __launch_bounds__(256) void fill_csr2(const int* __restrict__ eiA, const int* __restrict__ offA,
                                                 int* __restrict__ curA, int* __restrict__ srcsA,
                                                 const int* __restrict__ eiB, const int* __restrict__ offB,
                                                 int* __restrict__ curB, int* __restrict__ srcsB, int E) {
    int idx = blockIdx.x * 256 + threadIdx.x;
    int which = idx >= E;
    int e = idx - (which ? E : 0);
    if (e >= E) return;
    const int* ei = which ? eiB : eiA;
    const int* off = which ? offB : offA;
    int* cursor = which ? curB : curA;
    int* srcs = which ? srcsB : srcsA;
    int s = ei[e], d = ei[E + e];
    int slot = off[d] + atomicAdd(&cursor[d], 1);
    srcs[slot] = s;
}

// ---------------- 4. gather: one wave per dst node; out bf16 ------------------------
__global__ __launch_bounds__(256) void edge_gather2(const int* __restrict__ offA, const int* __restrict__ srcsA,
                                                    const float* __restrict__ asA, const float* __restrict__ adA,
                                                    const u16* __restrict__ hA, u16* __restrict__ outA,
                                                    const int* __restrict__ offB, const int* __restrict__ srcsB,
                                                    const float* __restrict__ asB, const float* __restrict__ adB,
                                                    const u16* __restrict__ hB, u16* __restrict__ outB, int N) {
    int gid = blockIdx.x * 256 + threadIdx.x;
    int dall = gid >> 6;
    int which = dall >= N;
    int d = dall - (which ? N : 0);
    if (d >= N) return;
    const int* off = which ? offB : offA;
    const int* srcs = which ? srcsB : srcsA;
    const float* a_src = which ? asB : asA;
    const float* a_dst = which ? adB : adA;
    const u16* h = which ? hB : hA;
    u16* out = which ? outB : outA;
    int lane = gid & 63;
    int hh = lane >> 5;
    int f = lane * 4;
    float ad0 = a_dst[d * 2 + hh];
    int beg = off[d], end = off[d + 1];
    float4 acc = {0.f, 0.f, 0.f, 0.f};
    float S = 0.f;
    for (int p = beg; p < end; ++p) {
        int s = srcs[p];
        float v = a_src[s * 2 + hh] + ad0;
        v = v > 0.f ? v : 0.2f * v;           // leaky_relu(0.2)
        float ex = __expf(v);
        S += ex;
        ushort4 xv = *(const ushort4*)(h + (size_t)s * 256 + f);
        acc.x += ex * bf2f(xv.x);
        acc.y += ex * bf2f(xv.y);
        acc.z += ex * bf2f(xv.z);
        acc.w += ex * bf2f(xv.w);
    }
    float inv = 1.f / (S + 1e-16f);
    ushort4 o = {f2bf(acc.x * inv), f2bf(acc.y * inv), f2bf(acc.z * inv), f2bf(acc.w * inv)};
    *(ushort4*)(out + (size_t)d * 256 + f) = o;
}

// ---------------- 5. semantic scores, both metapaths; A is bf16 ---------------------
#define SK 264
__global__ __launch_bounds__(256) void kgemm_score2(const u16* __restrict__ outA,
                                                    const u16* __restrict__ outB,
                                                    const float* __restrict__ kW,
                                                    const float* __restrict__ kb,
                                                    const float* __restrict__ qv,
                                                    float* __restrict__ score) {
    __shared__ u16 Bs[128 * SK];          // 66 KB
    __shared__ float red[4];
    int slot = blockIdx.x >> 8;           // 0..1
    int b = blockIdx.x & 255;
    const u16* outm = slot ? outB : outA;
    int bn = b & 1;
    int bidx = b >> 1;                    // 0..127
    int tid = threadIdx.x;
    int w = tid >> 6, lane = tid & 63;
    int row16 = lane & 15, quad = lane >> 4;

#pragma unroll
    for (int i = 0; i < 16; ++i) {
        int c = tid + 256 * i;
        int r = c >> 5, col8 = (c & 31) * 8;
        const float* src = kW + (size_t)(bn * 128 + r) * 256 + col8;
        *(bf16x8*)(Bs + r * SK + col8) = cvt8(*(const f32x4*)src, *(const f32x4*)(src + 4));
    }
    __syncthreads();

    float kb0 = kb[bn * 128 + w * 32 + row16];
    float qn0 = qv[bn * 128 + w * 32 + row16];
    float kb1 = kb[bn * 128 + w * 32 + 16 + row16];
    float qn1 = qv[bn * 128 + w * 32 + 16 + row16];
    const u16* b0 = Bs + (w * 32 + row16) * SK + quad * 8;
    const u16* b1 = Bs + (w * 32 + 16 + row16) * SK + quad * 8;

    union U { uint4 q; u16 s[8]; bf16x8 v; };
    float p = 0.f;
    for (int mt = bidx; mt < 1250; mt += 128) {
        const u16* arow = outm + (size_t)(mt * 16 + row16) * 256 + quad * 8;
        U a[8];
#pragma unroll
        for (int s8 = 0; s8 < 8; ++s8) a[s8].q = *(const uint4*)(arow + s8 * 32);
        f32x4 acc0 = {0.f,0.f,0.f,0.f}, acc1 = {0.f,0.f,0.f,0.f};
#pragma unroll
        for (int s8 = 0; s8 < 8; ++s8) {
#pragma unroll
            for (int j = 0; j < 8; ++j)       // relu in bf16 domain
                if (a[s8].s[j] & 0x8000u) a[s8].s[j] = 0;
            bf16x8 bf0 = *(const bf16x8*)(b0 + s8 * 32);
            bf16x8 bf1 = *(const bf16x8*)(b1 + s8 * 32);
            acc0 = __builtin_amdgcn_mfma_f32_16x16x32_bf16(a[s8].v, bf0, acc0, 0, 0, 0);
            acc1 = __builtin_amdgcn_mfma_f32_16x16x32_bf16(a[s8].v, bf1, acc1, 0, 0, 0);
        }
#pragma unroll
        for (int r = 0; r < 4; ++r) {
            p += qn0 * fast_tanh(acc0[r] + kb0);
            p += qn1 * fast_tanh(acc1[r] + kb1);
        }
    }
#pragma unroll
    for (int off = 32; off >= 1; off >>= 1) p += __shfl_down(p, off, 64);
    if (lane == 0) red[w] = p;
    __syncthreads();
    if (tid == 0) unsafeAtomicAdd(&score[slot], red[0] + red[1] + red[2] + red[3]);
}

// ---------------- 6. softmax over 2 metapath scores, blend, gather del_idx ----------
__global__ __launch_bounds__(256) void final_combine(const u16* __restrict__ out_ad,
                                                     const u16* __restrict__ out_dd,
                                                     const float* __restrict__ score,
                                                     const int* __restrict__ del_idx,
                                                     float* __restrict__ out) {
    int i = blockIdx.x;
    int f = threadIdx.x;
    int node = del_idx[i];
    float s0 = score[0] * (1.f / 20000.f);
    float s1 = score[1] * (1.f / 20000.f);
    float m = fmaxf(s0, s1);
    float e0 = __expf(s0 - m), e1 = __expf(s1 - m);
    float inv = 1.f / (e0 + e1);
    float a0 = e0 * inv, a1 = e1 * inv;
    float v0 = bf2f(out_ad[(size_t)node * 256 + f]); v0 = v0 > 0.f ? v0 : 0.f;
    float v1 = bf2f(out_dd[(size_t)node * 256 + f]); v1 = v1 > 0.f ? v1 : 0.f;
    out[(size_t)i * 256 + f] = a0 * v0 + a1 * v1;
}

extern "C" void kernel_launch(void* const* d_in, const int* in_sizes, int n_in,
                              void* d_out, int out_size, void* d_ws, size_t ws_size,
                              hipStream_t stream) {
    const float* x_add    = (const float*)d_in[0];
    const float* x_del    = (const float*)d_in[1];
    const float* W_add    = (const float*)d_in[2];
    const float* b_add    = (const float*)d_in[3];
    const float* W_del    = (const float*)d_in[4];
    const float* b_del    = (const float*)d_in[5];
    const float* att_ad_s = (const float*)d_in[6];
    const float* att_ad_d = (const float*)d_in[7];
    const float* att_dd_s = (const float*)d_in[12];
    const float* att_dd_d = (const float*)d_in[13];
    const float* k_W      = (const float*)d_in[14];
    const float* k_b      = (const float*)d_in[15];
    const float* q        = (const float*)d_in[16];
    const int* ei_ad      = (const int*)d_in[17];
    const int* ei_dd      = (const int*)d_in[20];
    const int* del_idx    = (const int*)d_in[21];
    float* out = (float*)d_out;

    const int N = 20000, E = 200000;
    char* ws = (char*)d_ws;
    size_t o = 0;
    // ---- zeroed region ----
    int* cnt_ad = (int*)(ws + o); o += (size_t)N * 4;
    int* cur_ad = (int*)(ws + o); o += (size_t)N * 4;
    int* cnt_dd = (int*)(ws + o); o += (size_t)N * 4;
    int* cur_dd = (int*)(ws + o); o += (size_t)N * 4;
    float* score = (float*)(ws + o); o += 256;
    size_t zero_bytes = o;
    // ---- written-once region ----
    u16* wb_add = (u16*)(ws + o); o += (size_t)256 * 768 * 2;
    u16* wb_del = (u16*)(ws + o); o += (size_t)256 * 768 * 2;
    int* off_ad = (int*)(ws + o); o += (size_t)(N + 1) * 4;
    int* off_dd = (int*)(ws + o); o += (size_t)(N + 1) * 4;
    int* srcs_ad = (int*)(ws + o); o += (size_t)E * 4;
    int* srcs_dd = (int*)(ws + o); o += (size_t)E * 4;
    u16* out_ad = (u16*)(ws + o); o += (size_t)N * 256 * 2;
    u16* out_dd = (u16*)(ws + o); o += (size_t)N * 256 * 2;
    u16* ha    = (u16*)(ws + o); o += (size_t)N * 256 * 2;
    u16* hd    = (u16*)(ws + o); o += (size_t)N * 256 * 2;
    float* as_ad = (float*)(ws + o); o += (size_t)N * 2 * 4;
    float* ad_ad = (float*)(ws + o); o += (size_t)N * 2 * 4;
    float* as_dd = (float*)(ws + o); o += (size_t)N * 2 * 4;
    float* ad_dd = (float*)(ws + o); o += (size_t)N * 2 * 4;

    hipMemsetAsync(d_ws, 0, zero_bytes, stream);

    cvt_w<<<192, 256, 0, stream>>>(W_add, wb_add, W_del, wb_del);

    // CSR build (fused pairs)
    count_edges2<<<(2 * E + 255) / 256, 256, 0, stream>>>(ei_ad, cnt_ad, ei_dd, cnt_dd, E);
    scan_two<<<2, 1024, 0, stream>>>(cnt_ad, off_ad, cnt_dd, off_dd, N);
    fill_csr2<<<(2 * E + 255) / 256, 256, 0, stream>>>(ei_ad, off_ad, cur_ad, srcs_ad,
                                                       ei_dd, off_dd, cur_dd, srcs_dd, E);

    // both projections: 2 * (157 m-tiles * 2 n-tiles) = 628 blocks
    gemm_h2<<<628, 256, 0, stream>>>(x_add, wb_add, b_add, ha,
                                     x_del, wb_del, b_del, hd, N);
    node_scores<<<5000, 256, 0, stream>>>(ha, hd, att_ad_s, att_ad_d, att_dd_s, att_dd_d,
                                          as_ad, ad_ad, as_dd, ad_dd, N);

    edge_gather2<<<10000, 256, 0, stream>>>(off_ad, srcs_ad, as_ad, ad_ad, ha, out_ad,
                                            off_dd, srcs_dd, as_dd, ad_dd, hd, out_dd, N);

    kgemm_score2<<<512, 256, 0, stream>>>(out_ad, out_dd, k_W, k_b, q, score);
    final_combine<<<4096, 256, 0, stream>>>(out_ad, out_dd, score, del_idx, out);
}

// Round 11
// 370.182 us; speedup vs baseline: 1.0555x; 1.0555x over previous
//
#include <hip/hip_runtime.h>
#include <hip/hip_bf16.h>

// HAN forward, del-branch only (add-branch _group output is unused in the reference).
// Inputs f32 / int32; output f32 [4096,256]. h and out_* stored bf16.
//
// R11: the ~91us gemm invariant across R6/R8/R9/R10 was GRID STARVATION
// (628 blocks = 2.45/CU vs a ~20-wave/CU resource ceiling). Fix: M-split.
//  - gemm_h2: BM=64 BN=128 BK=32 -> 1252 blocks (4.9/CU), LDS 30.7 KB, dbuf
//    1-barrier k-loop. X traffic unchanged (bn-pair adjacent => L2 A-sharing).
//  - W / k_W pre-converted to bf16 once; cvt fused into the count_edges dispatch.

typedef unsigned short u16;
typedef __attribute__((ext_vector_type(8))) __bf16 bf16x8;
typedef __attribute__((ext_vector_type(4))) float f32x4;

__device__ inline float bf2f(u16 u) {
    union { unsigned int i; float f; } c; c.i = ((unsigned int)u) << 16; return c.f;
}
__device__ inline u16 f2bf(float f) {  // round-to-nearest-even
    union { float f; unsigned int i; } c; c.f = f;
    return (u16)((c.i + 0x7fffu + ((c.i >> 16) & 1u)) >> 16);
}
__device__ inline bf16x8 cvt8(f32x4 a, f32x4 b) {
    bf16x8 r;
    r[0] = (__bf16)a[0]; r[1] = (__bf16)a[1]; r[2] = (__bf16)a[2]; r[3] = (__bf16)a[3];
    r[4] = (__bf16)b[0]; r[5] = (__bf16)b[1]; r[6] = (__bf16)b[2]; r[7] = (__bf16)b[3];
    return r;
}
__device__ inline float fast_tanh(float x) {
    x = fminf(9.f, fmaxf(-9.f, x));
    float t = __expf(2.f * x);
    return (t - 1.f) / (t + 1.f);
}

// ---------------- 0. prep: W/kW f32->bf16 cvt + degree histogram (one dispatch) -----
__global__ __launch_bounds__(256) void prep_count(const float* __restrict__ W0, u16* __restrict__ wb0,
                                                  const float* __restrict__ W1, u16* __restrict__ wb1,
                                                  const float* __restrict__ kW, u16* __restrict__ kwb,
                                                  const int* __restrict__ eiA, int* __restrict__ cntA,
                                                  const int* __restrict__ eiB, int* __restrict__ cntB, int E) {
    int b = blockIdx.x;
    if (b < 224) {                        // 57344 chunks of 8 = W0|W1|kW exactly
        int idx = b * 256 + threadIdx.x;
        const float* s; u16* d; int i;
        if (idx < 24576)      { s = W0; d = wb0; i = idx; }
        else if (idx < 49152) { s = W1; d = wb1; i = idx - 24576; }
        else                  { s = kW; d = kwb; i = idx - 49152; }
        int e = i * 8;
        *(bf16x8*)(d + e) = cvt8(*(const f32x4*)(s + e), *(const f32x4*)(s + e + 4));
    } else {
        int idx = (b - 224) * 256 + threadIdx.x;
        int which = idx >= E;
        int e = idx - (which ? E : 0);
        if (e >= E) return;
        const int* ei = which ? eiB : eiA;
        int* cnt = which ? cntB : cntA;
        atomicAdd(&cnt[ei[E + e]], 1);
    }
}

// ---------------- 1. h = X @ W^T + b, BM=64 BN=128, 1252 blocks ---------------------
// 4 waves 2x2: wave = 32 rows x 64 cols = 2x4 frags = 8 MFMA/kstep. LDS dbuf 30 KB.
#define SA 40
__global__ __launch_bounds__(256) void gemm_h2(const float* __restrict__ X0, const u16* __restrict__ Wb0,
                                               const float* __restrict__ b0, u16* __restrict__ H0,
                                               const float* __restrict__ X1, const u16* __restrict__ Wb1,
                                               const float* __restrict__ b1, u16* __restrict__ H1, int M) {
    __shared__ u16 smem[15360];          // As: 2 x 64*40 (5120) | Bs: 2 x 128*40 (10240)
    u16* As[2] = { smem, smem + 2560 };
    u16* Bs[2] = { smem + 5120, smem + 10240 };
    int id = blockIdx.x;
    int which = id >= 626;
    if (which) id -= 626;
    int bm = id >> 1, bn = id & 1;       // bn-pair adjacent: L2 A-sharing
    const float* X = which ? X1 : X0;
    const u16* Wb = which ? Wb1 : Wb0;
    const float* bias = which ? b1 : b0;
    u16* H = which ? H1 : H0;

    int tid = threadIdx.x;
    int w = tid >> 6, lane = tid & 63;
    int wm = w & 1, wn = w >> 1;
    int row16 = lane & 15, quad = lane >> 4;

    // A staging: thread -> row ra (0..63), chunk ca; one bf16x8 per kstep
    int ra = tid >> 2, ca = (tid & 3) * 8;
    int ar = bm * 64 + ra; if (ar > M - 1) ar = M - 1;
    const float* ag = X + (size_t)ar * 768 + ca;
    int aoff = ra * SA + ca;
    // B staging: thread -> chunks tid, tid+256 of 512 (128 rows x 4 chunks)
    int rb0 = tid >> 2, rb1 = (tid + 256) >> 2;
    const u16* bg0 = Wb + (size_t)(bn * 128 + rb0) * 768 + ca;
    const u16* bg1 = Wb + (size_t)(bn * 128 + rb1) * 768 + ca;
    int boff0 = rb0 * SA + ca, boff1 = rb1 * SA + ca;

    int ardo = (wm * 32 + row16) * SA + quad * 8;
    int brdo = (wn * 64 + row16) * SA + quad * 8;

    f32x4 ra0, ra1;
    bf16x8 rbv0, rbv1;
#define LOADT(k) { ra0 = *(const f32x4*)(ag + (k)); ra1 = *(const f32x4*)(ag + (k) + 4); \
                   rbv0 = *(const bf16x8*)(bg0 + (k)); rbv1 = *(const bf16x8*)(bg1 + (k)); }
#define WRITET(b) { *(bf16x8*)(As[b] + aoff) = cvt8(ra0, ra1); \
                    *(bf16x8*)(Bs[b] + boff0) = rbv0; \
                    *(bf16x8*)(Bs[b] + boff1) = rbv1; }

    LOADT(0)
    WRITET(0)
    __syncthreads();

    f32x4 acc[2][4] = {};
#pragma unroll
    for (int ks = 0; ks < 24; ++ks) {
        int cur = ks & 1;
        if (ks < 23) LOADT((ks + 1) * 32)
        bf16x8 af[2], bv[4];
#pragma unroll
        for (int i = 0; i < 2; ++i) af[i] = *(const bf16x8*)(As[cur] + ardo + i * 16 * SA);
#pragma unroll
        for (int i = 0; i < 4; ++i) bv[i] = *(const bf16x8*)(Bs[cur] + brdo + i * 16 * SA);
#pragma unroll
        for (int mi = 0; mi < 2; ++mi)
#pragma unroll
            for (int ni = 0; ni < 4; ++ni)
                acc[mi][ni] = __builtin_amdgcn_mfma_f32_16x16x32_bf16(af[mi], bv[ni], acc[mi][ni], 0, 0, 0);
        if (ks < 23) {
            WRITET(cur ^ 1)
            __syncthreads();
        }
    }
#undef LOADT
#undef WRITET

    // ---- coalesced epilogue via LDS: 64 rows x 136 stride (17.4 KB, reuse smem) ----
    __syncthreads();
    u16* eps = smem;
    const int SE2 = 136;
#pragma unroll
    for (int ni = 0; ni < 4; ++ni) {
        int lcol = wn * 64 + ni * 16 + row16;
        float bvv = bias[bn * 128 + lcol];
#pragma unroll
        for (int mi = 0; mi < 2; ++mi)
#pragma unroll
            for (int r = 0; r < 4; ++r)
                eps[(wm * 32 + mi * 16 + quad * 4 + r) * SE2 + lcol] = f2bf(acc[mi][ni][r] + bvv);
    }
    __syncthreads();
    int mlim = M - bm * 64;
#pragma unroll
    for (int p = 0; p < 4; ++p) {
        int row = p * 16 + (tid >> 4);
        if (row < mlim) {
            int chunk = (tid & 15) * 8;
            uint4 v = *(const uint4*)(eps + row * SE2 + chunk);
            *(uint4*)(H + (size_t)(bm * 64 + row) * 256 + bn * 128 + chunk) = v;
        }
    }
}

// ---------------- 2. per-(node,head) attention scores (h bf16) ----------------------
__global__ __launch_bounds__(256) void node_scores(const u16* __restrict__ ha, const u16* __restrict__ hd,
                                                   const float* __restrict__ w_ads, const float* __restrict__ w_add,
                                                   const float* __restrict__ w_dds, const float* __restrict__ w_ddd,
                                                   float* __restrict__ as_ad, float* __restrict__ ad_ad,
                                                   float* __restrict__ as_dd, float* __restrict__ ad_dd, int N) {
    int gid = blockIdx.x * 256 + threadIdx.x;
    int n = gid >> 6;
    if (n >= N) return;
    int lane = gid & 63;
    int f = lane * 4;
    ushort4 av = *(const ushort4*)(ha + (size_t)n * 256 + f);
    ushort4 dv = *(const ushort4*)(hd + (size_t)n * 256 + f);
    float4 w1 = *(const float4*)(w_ads + f);
    float4 w2 = *(const float4*)(w_add + f);
    float4 w3 = *(const float4*)(w_dds + f);
    float4 w4 = *(const float4*)(w_ddd + f);
    float a0 = bf2f(av.x), a1 = bf2f(av.y), a2 = bf2f(av.z), a3 = bf2f(av.w);
    float d0 = bf2f(dv.x), d1 = bf2f(dv.y), d2 = bf2f(dv.z), d3 = bf2f(dv.w);
    float p1 = a0 * w1.x + a1 * w1.y + a2 * w1.z + a3 * w1.w;
    float p2 = d0 * w2.x + d1 * w2.y + d2 * w2.z + d3 * w2.w;
    float p3 = d0 * w3.x + d1 * w3.y + d2 * w3.z + d3 * w3.w;
    float p4 = d0 * w4.x + d1 * w4.y + d2 * w4.z + d3 * w4.w;
#pragma unroll
    for (int off = 16; off >= 1; off >>= 1) {
        p1 += __shfl_down(p1, off, 32);
        p2 += __shfl_down(p2, off, 32);
        p3 += __shfl_down(p3, off, 32);
        p4 += __shfl_down(p4, off, 32);
    }
    if ((lane & 31) == 0) {
        int h = lane >> 5;
        as_ad[n * 2 + h] = p1;
        ad_ad[n * 2 + h] = p2;
        as_dd[n * 2 + h] = p3;
        ad_dd[n * 2 + h] = p4;
    }
}

// ---------------- 3b. exclusive scan, int4-blocked ----------------------------------
__global__ __launch_bounds__(1024) void scan_two(const int* __restrict__ cntA, int* __restrict__ offA,
                                                 const int* __restrict__ cntB, int* __restrict__ offB, int n) {
    const int* cnt = blockIdx.x ? cntB : cntA;
    int* off = blockIdx.x ? offB : offA;
    __shared__ int wsum[16];
    __shared__ int woff[16];
    __shared__ int tot_s;
    __shared__ int carry_s;
    int tid = threadIdx.x, wid = tid >> 6, lane = tid & 63;
    if (tid == 0) carry_s = 0;
    __syncthreads();
    for (int base = 0; base < n; base += 4096) {
        int i = base + tid * 4;
        int v0 = (i + 0 < n) ? cnt[i + 0] : 0;
        int v1 = (i + 1 < n) ? cnt[i + 1] : 0;
        int v2 = (i + 2 < n) ? cnt[i + 2] : 0;
        int v3 = (i + 3 < n) ? cnt[i + 3] : 0;
        int s0 = v0, s1 = s0 + v1, s2 = s1 + v2, s3 = s2 + v3;
        int x = s3;
#pragma unroll
        for (int d = 1; d < 64; d <<= 1) {
            int t = __shfl_up(x, d, 64);
            if (lane >= d) x += t;
        }
        if (lane == 63) wsum[wid] = x;
        __syncthreads();
        if (wid == 0) {
            int s = (lane < 16) ? wsum[lane] : 0;
#pragma unroll
            for (int d = 1; d < 16; d <<= 1) {
                int t = __shfl_up(s, d, 64);
                if (lane >= d) s += t;
            }
            if (lane < 16) woff[lane] = s - wsum[lane];
            if (lane == 15) tot_s = s;
        }
        __syncthreads();
        int basev = carry_s + woff[wid] + (x - s3);
        if (i + 0 < n) off[i + 0] = basev;
        if (i + 1 < n) off[i + 1] = basev + s0;
        if (i + 2 < n) off[i + 2] = basev + s1;
        if (i + 3 < n) off[i + 3] = basev + s2;
        __syncthreads();
        if (tid == 0) carry_s += tot_s;
    }
    __syncthreads();
    if (tid == 0) off[n] = carry_s;
}

// ---------------- 3c. fill CSR src lists, both edge sets ----------------------------
__global__ __launch_bounds__(256) void fill_csr2(const int* __restrict__ eiA, const int* __restrict__ offA,
                                                 int* __restrict__ curA, int* __restrict__ srcsA,
                                                 const int* __restrict__ eiB, const int* __restrict__ offB,
                                                 int* __restrict__ curB, int* __restrict__ srcsB, int E) {
    int idx = blockIdx.x * 256 + threadIdx.x;
    int which = idx >= E;
    int e = idx - (which ? E : 0);
    if (e >= E) return;
    const int* ei = which ? eiB : eiA;
    const int* off = which ? offB : offA;
    int* cursor = which ? curB : curA;
    int* srcs = which ? srcsB : srcsA;
    int s = ei[e], d = ei[E + e];
    int slot = off[d] + atomicAdd(&cursor[d], 1);
    srcs[slot] = s;
}

// ---------------- 4. gather: one wave per dst node; out bf16 ------------------------
__global__ __launch_bounds__(256) void edge_gather2(const int* __restrict__ offA, const int* __restrict__ srcsA,
                                                    const float* __restrict__ asA, const float* __restrict__ adA,
                                                    const u16* __restrict__ hA, u16* __restrict__ outA,
                                                    const int* __restrict__ offB, const int* __restrict__ srcsB,
                                                    const float* __restrict__ asB, const float* __restrict__ adB,
                                                    const u16* __restrict__ hB, u16* __restrict__ outB, int N) {
    int gid = blockIdx.x * 256 + threadIdx.x;
    int dall = gid >> 6;
    int which = dall >= N;
    int d = dall - (which ? N : 0);
    if (d >= N) return;
    const int* off = which ? offB : offA;
    const int* srcs = which ? srcsB : srcsA;
    const float* a_src = which ? asB : asA;
    const float* a_dst = which ? adB : adA;
    const u16* h = which ? hB : hA;
    u16* out = which ? outB : outA;
    int lane = gid & 63;
    int hh = lane >> 5;
    int f = lane * 4;
    float ad0 = a_dst[d * 2 + hh];
    int beg = off[d], end = off[d + 1];
    float4 acc = {0.f, 0.f, 0.f, 0.f};
    float S = 0.f;
    for (int p = beg; p < end; ++p) {
        int s = srcs[p];
        float v = a_src[s * 2 + hh] + ad0;
        v = v > 0.f ? v : 0.2f * v;           // leaky_relu(0.2)
        float ex = __expf(v);
        S += ex;
        ushort4 xv = *(const ushort4*)(h + (size_t)s * 256 + f);
        acc.x += ex * bf2f(xv.x);
        acc.y += ex * bf2f(xv.y);
        acc.z += ex * bf2f(xv.z);
        acc.w += ex * bf2f(xv.w);
    }
    float inv = 1.f / (S + 1e-16f);
    ushort4 o = {f2bf(acc.x * inv), f2bf(acc.y * inv), f2bf(acc.z * inv), f2bf(acc.w * inv)};
    *(ushort4*)(out + (size_t)d * 256 + f) = o;
}

// ---------------- 5. semantic scores; A bf16, kW pre-converted bf16 -----------------
#define SK 264
__global__ __launch_bounds__(256) void kgemm_score2(const u16* __restrict__ outA,
                                                    const u16* __restrict__ outB,
                                                    const u16* __restrict__ kwb,
                                                    const float* __restrict__ kb,
                                                    const float* __restrict__ qv,
                                                    float* __restrict__ score) {
    __shared__ u16 Bs[128 * SK];          // 66 KB
    __shared__ float red[4];
    int slot = blockIdx.x >> 8;           // 0..1
    int b = blockIdx.x & 255;
    const u16* outm = slot ? outB : outA;
    int bn = b & 1;
    int bidx = b >> 1;                    // 0..127
    int tid = threadIdx.x;
    int w = tid >> 6, lane = tid & 63;
    int row16 = lane & 15, quad = lane >> 4;

#pragma unroll
    for (int i = 0; i < 16; ++i) {
        int c = tid + 256 * i;
        int r = c >> 5, col8 = (c & 31) * 8;
        *(bf16x8*)(Bs + r * SK + col8) = *(const bf16x8*)(kwb + (size_t)(bn * 128 + r) * 256 + col8);
    }
    __syncthreads();

    float kb0 = kb[bn * 128 + w * 32 + row16];
    float qn0 = qv[bn * 128 + w * 32 + row16];
    float kb1 = kb[bn * 128 + w * 32 + 16 + row16];
    float qn1 = qv[bn * 128 + w * 32 + 16 + row16];
    const u16* b0 = Bs + (w * 32 + row16) * SK + quad * 8;
    const u16* b1 = Bs + (w * 32 + 16 + row16) * SK + quad * 8;

    union U { uint4 q; u16 s[8]; bf16x8 v; };
    float p = 0.f;
    for (int mt = bidx; mt < 1250; mt += 128) {
        const u16* arow = outm + (size_t)(mt * 16 + row16) * 256 + quad * 8;
        U a[8];
#pragma unroll
        for (int s8 = 0; s8 < 8; ++s8) a[s8].q = *(const uint4*)(arow + s8 * 32);
        f32x4 acc0 = {0.f,0.f,0.f,0.f}, acc1 = {0.f,0.f,0.f,0.f};
#pragma unroll
        for (int s8 = 0; s8 < 8; ++s8) {
#pragma unroll
            for (int j = 0; j < 8; ++j)       // relu in bf16 domain
                if (a[s8].s[j] & 0x8000u) a[s8].s[j] = 0;
            bf16x8 bf0 = *(const bf16x8*)(b0 + s8 * 32);
            bf16x8 bf1 = *(const bf16x8*)(b1 + s8 * 32);
            acc0 = __builtin_amdgcn_mfma_f32_16x16x32_bf16(a[s8].v, bf0, acc0, 0, 0, 0);
            acc1 = __builtin_amdgcn_mfma_f32_16x16x32_bf16(a[s8].v, bf1, acc1, 0, 0, 0);
        }
#pragma unroll
        for (int r = 0; r < 4; ++r) {
            p += qn0 * fast_tanh(acc0[r] + kb0);
            p += qn1 * fast_tanh(acc1[r] + kb1);
        }
    }
#pragma unroll
    for (int off = 32; off >= 1; off >>= 1) p += __shfl_down(p, off, 64);
    if (lane == 0) red[w] = p;
    __syncthreads();
    if (tid == 0) unsafeAtomicAdd(&score[slot], red[0] + red[1] + red[2] + red[3]);
}

// ---------------- 6. softmax over 2 metapath scores, blend, gather del_idx ----------
__global__ __launch_bounds__(256) void final_combine(const u16* __restrict__ out_ad,
                                                     const u16* __restrict__ out_dd,
                                                     const float* __restrict__ score,
                                                     const int* __restrict__ del_idx,
                                                     float* __restrict__ out) {
    int i = blockIdx.x;
    int f = threadIdx.x;
    int node = del_idx[i];
    float s0 = score[0] * (1.f / 20000.f);
    float s1 = score[1] * (1.f / 20000.f);
    float m = fmaxf(s0, s1);
    float e0 = __expf(s0 - m), e1 = __expf(s1 - m);
    float inv = 1.f / (e0 + e1);
    float a0 = e0 * inv, a1 = e1 * inv;
    float v0 = bf2f(out_ad[(size_t)node * 256 + f]); v0 = v0 > 0.f ? v0 : 0.f;
    float v1 = bf2f(out_dd[(size_t)node * 256 + f]); v1 = v1 > 0.f ? v1 : 0.f;
    out[(size_t)i * 256 + f] = a0 * v0 + a1 * v1;
}

extern "C" void kernel_launch(void* const* d_in, const int* in_sizes, int n_in,
                              void* d_out, int out_size, void* d_ws, size_t ws_size,
                              hipStream_t stream) {
    const float* x_add    = (const float*)d_in[0];
    const float* x_del    = (const float*)d_in[1];
    const float* W_add    = (const float*)d_in[2];
    const float* b_add    = (const float*)d_in[3];
    const float* W_del    = (const float*)d_in[4];
    const float* b_del    = (const float*)d_in[5];
    const float* att_ad_s = (const float*)d_in[6];
    const float* att_ad_d = (const float*)d_in[7];
    const float* att_dd_s = (const float*)d_in[12];
    const float* att_dd_d = (const float*)d_in[13];
    const float* k_W      = (const float*)d_in[14];
    const float* k_b      = (const float*)d_in[15];
    const float* q        = (const float*)d_in[16];
    const int* ei_ad      = (const int*)d_in[17];
    const int* ei_dd      = (const int*)d_in[20];
    const int* del_idx    = (const int*)d_in[21];
    float* out = (float*)d_out;

    const int N = 20000, E = 200000;
    char* ws = (char*)d_ws;
    size_t o = 0;
    // ---- zeroed region ----
    int* cnt_ad = (int*)(ws + o); o += (size_t)N * 4;
    int* cur_ad = (int*)(ws + o); o += (size_t)N * 4;
    int* cnt_dd = (int*)(ws + o); o += (size_t)N * 4;
    int* cur_dd = (int*)(ws + o); o += (size_t)N * 4;
    float* score = (float*)(ws + o); o += 256;
    size_t zero_bytes = o;
    // ---- written-once region ----
    u16* wb_add = (u16*)(ws + o); o += (size_t)256 * 768 * 2;
    u16* wb_del = (u16*)(ws + o); o += (size_t)256 * 768 * 2;
    u16* kwb    = (u16*)(ws + o); o += (size_t)256 * 256 * 2;
    int* off_ad = (int*)(ws + o); o += (size_t)(N + 1) * 4;
    int* off_dd = (int*)(ws + o); o += (size_t)(N + 1) * 4;
    int* srcs_ad = (int*)(ws + o); o += (size_t)E * 4;
    int* srcs_dd = (int*)(ws + o); o += (size_t)E * 4;
    u16* out_ad = (u16*)(ws + o); o += (size_t)N * 256 * 2;
    u16* out_dd = (u16*)(ws + o); o += (size_t)N * 256 * 2;
    u16* ha    = (u16*)(ws + o); o += (size_t)N * 256 * 2;
    u16* hd    = (u16*)(ws + o); o += (size_t)N * 256 * 2;
    float* as_ad = (float*)(ws + o); o += (size_t)N * 2 * 4;
    float* ad_ad = (float*)(ws + o); o += (size_t)N * 2 * 4;
    float* as_dd = (float*)(ws + o); o += (size_t)N * 2 * 4;
    float* ad_dd = (float*)(ws + o); o += (size_t)N * 2 * 4;

    hipMemsetAsync(d_ws, 0, zero_bytes, stream);

    // W/kW cvt + degree histogram, one dispatch
    prep_count<<<224 + (2 * E + 255) / 256, 256, 0, stream>>>(
        W_add, wb_add, W_del, wb_del, k_W, kwb, ei_ad, cnt_ad, ei_dd, cnt_dd, E);
    scan_two<<<2, 1024, 0, stream>>>(cnt_ad, off_ad, cnt_dd, off_dd, N);
    fill_csr2<<<(2 * E + 255) / 256, 256, 0, stream>>>(ei_ad, off_ad, cur_ad, srcs_ad,
                                                       ei_dd, off_dd, cur_dd, srcs_dd, E);

    // both projections: 2 * (313 m-tiles * 2 n-tiles) = 1252 blocks
    gemm_h2<<<1252, 256, 0, stream>>>(x_add, wb_add, b_add, ha,
                                      x_del, wb_del, b_del, hd, N);
    node_scores<<<5000, 256, 0, stream>>>(ha, hd, att_ad_s, att_ad_d, att_dd_s, att_dd_d,
                                          as_ad, ad_ad, as_dd, ad_dd, N);

    edge_gather2<<<10000, 256, 0, stream>>>(off_ad, srcs_ad, as_ad, ad_ad, ha, out_ad,
                                            off_dd, srcs_dd, as_dd, ad_dd, hd, out_dd, N);

    kgemm_score2<<<512, 256, 0, stream>>>(out_ad, out_dd, kwb, k_b, q, score);
    final_combine<<<4096, 256, 0, stream>>>(out_ad, out_dd, score, del_idx, out);
}

// Round 12
// 349.646 us; speedup vs baseline: 1.1175x; 1.0587x over previous
//
#include <hip/hip_runtime.h>
#include <hip/hip_bf16.h>

// HAN forward, del-branch only (add-branch _group output is unused in the reference).
// Inputs f32 / int32; output f32 [4096,256]. h and out_* stored bf16.
//
// R12:
//  - gemm_h2: global_load_lds triple-buffer (48 KB, 3 blk/CU) x 1252-block grid.
//    Per-wave `s_waitcnt vmcnt(4)` + raw s_barrier: each wave's own tile-k DMAs
//    done before the barrier => tile globally ready after it; prefetch DMAs for
//    k+1,k+2 stay in flight across the barrier (no vmcnt(0) drain).
//    XOR-swizzled LDS (A: chunk^=(row&7), B: chunk^=((row>>1)&3)) => 2-way max.
//  - node_scores fused into gemm epilogue (h tile already in LDS; head == bn).
//  - edge_gather2: 2-edge unroll (2 independent gather chains in flight).

typedef unsigned short u16;
typedef __attribute__((ext_vector_type(8))) __bf16 bf16x8;
typedef __attribute__((ext_vector_type(4))) float f32x4;
typedef const __attribute__((address_space(1))) unsigned int* gu32p;
typedef __attribute__((address_space(3))) unsigned int* su32p;

__device__ inline float bf2f(u16 u) {
    union { unsigned int i; float f; } c; c.i = ((unsigned int)u) << 16; return c.f;
}
__device__ inline u16 f2bf(float f) {  // round-to-nearest-even
    union { float f; unsigned int i; } c; c.f = f;
    return (u16)((c.i + 0x7fffu + ((c.i >> 16) & 1u)) >> 16);
}
__device__ inline bf16x8 cvt8(f32x4 a, f32x4 b) {
    bf16x8 r;
    r[0] = (__bf16)a[0]; r[1] = (__bf16)a[1]; r[2] = (__bf16)a[2]; r[3] = (__bf16)a[3];
    r[4] = (__bf16)b[0]; r[5] = (__bf16)b[1]; r[6] = (__bf16)b[2]; r[7] = (__bf16)b[3];
    return r;
}
__device__ inline float fast_tanh(float x) {
    x = fminf(9.f, fmaxf(-9.f, x));
    float t = __expf(2.f * x);
    return (t - 1.f) / (t + 1.f);
}

// ---------------- 0. prep: W/kW f32->bf16 cvt + degree histogram (one dispatch) -----
__global__ __launch_bounds__(256) void prep_count(const float* __restrict__ W0, u16* __restrict__ wb0,
                                                  const float* __restrict__ W1, u16* __restrict__ wb1,
                                                  const float* __restrict__ kW, u16* __restrict__ kwb,
                                                  const int* __restrict__ eiA, int* __restrict__ cntA,
                                                  const int* __restrict__ eiB, int* __restrict__ cntB, int E) {
    int b = blockIdx.x;
    if (b < 224) {                        // 57344 chunks of 8 = W0|W1|kW exactly
        int idx = b * 256 + threadIdx.x;
        const float* s; u16* d; int i;
        if (idx < 24576)      { s = W0; d = wb0; i = idx; }
        else if (idx < 49152) { s = W1; d = wb1; i = idx - 24576; }
        else                  { s = kW; d = kwb; i = idx - 49152; }
        int e = i * 8;
        *(bf16x8*)(d + e) = cvt8(*(const f32x4*)(s + e), *(const f32x4*)(s + e + 4));
    } else {
        int idx = (b - 224) * 256 + threadIdx.x;
        int which = idx >= E;
        int e = idx - (which ? E : 0);
        if (e >= E) return;
        const int* ei = which ? eiB : eiA;
        int* cnt = which ? cntB : cntA;
        atomicAdd(&cnt[ei[E + e]], 1);
    }
}

// ---------------- 1. h = X @ W^T + b (+ fused attention-score dots) -----------------
// BM=64 BN=128 BK=32; 1252 blocks; 4 waves 2x2 (wave 32x64 = 2x4 frags, 8 MFMA/kstep).
// A f32 and B bf16 DMA'd direct to LDS, triple-buffered, XOR-swizzled.
__global__ __launch_bounds__(256) void gemm_h2(
    const float* __restrict__ X0, const u16* __restrict__ Wb0,
    const float* __restrict__ b0, u16* __restrict__ H0,
    const float* __restrict__ X1, const u16* __restrict__ Wb1,
    const float* __restrict__ b1, u16* __restrict__ H1,
    const float* __restrict__ w_ads, const float* __restrict__ w_add,
    const float* __restrict__ w_dds, const float* __restrict__ w_ddd,
    float* __restrict__ as_ad, float* __restrict__ ad_ad,
    float* __restrict__ as_dd, float* __restrict__ ad_dd, int M) {
    __shared__ float Af[3][2048];        // 3 x 8 KB: 64 rows x 32 f32, chunk-swizzled
    __shared__ u16   Bb[3][4096];        // 3 x 8 KB: 128 rows x 32 bf16, chunk-swizzled
    int id = blockIdx.x;
    int which = id >= 626;
    if (which) id -= 626;
    int bm = id >> 1, bn = id & 1;
    const float* X = which ? X1 : X0;
    const u16* Wb = which ? Wb1 : Wb0;
    const float* bias = which ? b1 : b0;
    u16* H = which ? H1 : H0;

    int tid = threadIdx.x;
    int w = tid >> 6, lane = tid & 63;
    int wm = w & 1, wn = w >> 1;
    int row16 = lane & 15, quad = lane >> 4;

// tile kt -> buffer b: per wave 2 A-DMAs (8 rows each) + 2 B-DMAs (16 rows each)
#define ISSUE(kt, b) { \
    int kA = (kt) * 32; \
    _Pragma("unroll") \
    for (int j = 0; j < 2; ++j) { \
        int rloc = (w * 2 + j) * 8 + (lane >> 3); \
        int rg = bm * 64 + rloc; if (rg > M - 1) rg = M - 1; \
        int c = (lane & 7) ^ (rloc & 7); \
        const float* gp = X + (size_t)rg * 768 + kA + c * 4; \
        float* lp = Af[b] + (w * 2 + j) * 256; \
        __builtin_amdgcn_global_load_lds((gu32p)(const void*)gp, (su32p)(void*)lp, 16, 0, 0); \
    } \
    _Pragma("unroll") \
    for (int j = 0; j < 2; ++j) { \
        int rloc = (w * 2 + j) * 16 + (lane >> 2); \
        int c = (lane & 3) ^ ((rloc >> 1) & 3); \
        const u16* gp = Wb + (size_t)(bn * 128 + rloc) * 768 + kA + c * 8; \
        u16* lp = Bb[b] + (w * 2 + j) * 512; \
        __builtin_amdgcn_global_load_lds((gu32p)(const void*)gp, (su32p)(void*)lp, 16, 0, 0); \
    } }

    ISSUE(0, 0)
    ISSUE(1, 1)

    f32x4 acc[2][4] = {};
#pragma unroll
    for (int ks = 0; ks < 24; ++ks) {
        int cur = ks % 3;
        if (ks < 23) { asm volatile("s_waitcnt vmcnt(4)" ::: "memory"); }
        else         { asm volatile("s_waitcnt vmcnt(0)" ::: "memory"); }
        asm volatile("s_barrier" ::: "memory");
        if (ks + 2 < 24) { int nb = (ks + 2) % 3; ISSUE(ks + 2, nb) }
        bf16x8 af[2], bv[4];
#pragma unroll
        for (int mi = 0; mi < 2; ++mi) {
            int r = wm * 32 + mi * 16 + row16;
            int c0 = (2 * quad) ^ (r & 7), c1 = (2 * quad + 1) ^ (r & 7);
            f32x4 f0 = *(const f32x4*)(Af[cur] + r * 32 + c0 * 4);
            f32x4 f1 = *(const f32x4*)(Af[cur] + r * 32 + c1 * 4);
            af[mi] = cvt8(f0, f1);
        }
#pragma unroll
        for (int ni = 0; ni < 4; ++ni) {
            int r = wn * 64 + ni * 16 + row16;
            int c = quad ^ ((r >> 1) & 3);
            bv[ni] = *(const bf16x8*)(Bb[cur] + r * 32 + c * 8);
        }
#pragma unroll
        for (int mi = 0; mi < 2; ++mi)
#pragma unroll
            for (int ni = 0; ni < 4; ++ni)
                acc[mi][ni] = __builtin_amdgcn_mfma_f32_16x16x32_bf16(af[mi], bv[ni], acc[mi][ni], 0, 0, 0);
    }
#undef ISSUE

    // ---- epilogue: acc -> LDS bf16, coalesced store + fused att-score dots ----
    __syncthreads();
    u16* eps = (u16*)Af;                 // 64 x 136 u16 = 17.4 KB (fits in Af's 24 KB)
    const int SE2 = 136;
#pragma unroll
    for (int ni = 0; ni < 4; ++ni) {
        int lcol = wn * 64 + ni * 16 + row16;
        float bvv = bias[bn * 128 + lcol];
#pragma unroll
        for (int mi = 0; mi < 2; ++mi)
#pragma unroll
            for (int r = 0; r < 4; ++r)
                eps[(wm * 32 + mi * 16 + quad * 4 + r) * SE2 + lcol] = f2bf(acc[mi][ni][r] + bvv);
    }
    __syncthreads();
    int mlim = M - bm * 64;
    int c0 = (tid & 15) * 8;             // 8 cols of the 128-col (= head bn) slice
    // att weights for these cols
    float wv[3][8];
    int nw = which ? 3 : 1;
    const float* att0 = which ? w_add : w_ads;
    const float* att1 = w_dds;
    const float* att2 = w_ddd;
#pragma unroll
    for (int j = 0; j < 8; ++j) {
        wv[0][j] = att0[bn * 128 + c0 + j];
        wv[1][j] = att1[bn * 128 + c0 + j];
        wv[2][j] = att2[bn * 128 + c0 + j];
    }
#pragma unroll
    for (int p = 0; p < 4; ++p) {
        int row = p * 16 + (tid >> 4);
        uint4 v = *(const uint4*)(eps + row * SE2 + c0);
        if (row < mlim)
            *(uint4*)(H + (size_t)(bm * 64 + row) * 256 + bn * 128 + c0) = v;
        // score dots on the same LDS row chunk
        float d0 = 0.f, d1 = 0.f, d2 = 0.f;
#pragma unroll
        for (int j = 0; j < 8; ++j) {
            float hv = bf2f(eps[row * SE2 + c0 + j]);
            d0 += hv * wv[0][j];
            if (which) { d1 += hv * wv[1][j]; d2 += hv * wv[2][j]; }
        }
#pragma unroll
        for (int off = 8; off >= 1; off >>= 1) {
            d0 += __shfl_down(d0, off, 16);
            if (which) { d1 += __shfl_down(d1, off, 16); d2 += __shfl_down(d2, off, 16); }
        }
        if ((tid & 15) == 0 && row < mlim) {
            int n = bm * 64 + row;
            if (!which) {
                unsafeAtomicAdd(&as_ad[n * 2 + bn], d0);
            } else {
                unsafeAtomicAdd(&ad_ad[n * 2 + bn], d0);
                unsafeAtomicAdd(&as_dd[n * 2 + bn], d1);
                unsafeAtomicAdd(&ad_dd[n * 2 + bn], d2);
            }
        }
    }
}

// ---------------- 3b. exclusive scan, int4-blocked ----------------------------------
__global__ __launch_bounds__(1024) void scan_two(const int* __restrict__ cntA, int* __restrict__ offA,
                                                 const int* __restrict__ cntB, int* __restrict__ offB, int n) {
    const int* cnt = blockIdx.x ? cntB : cntA;
    int* off = blockIdx.x ? offB : offA;
    __shared__ int wsum[16];
    __shared__ int woff[16];
    __shared__ int tot_s;
    __shared__ int carry_s;
    int tid = threadIdx.x, wid = tid >> 6, lane = tid & 63;
    if (tid == 0) carry_s = 0;
    __syncthreads();
    for (int base = 0; base < n; base += 4096) {
        int i = base + tid * 4;
        int v0 = (i + 0 < n) ? cnt[i + 0] : 0;
        int v1 = (i + 1 < n) ? cnt[i + 1] : 0;
        int v2 = (i + 2 < n) ? cnt[i + 2] : 0;
        int v3 = (i + 3 < n) ? cnt[i + 3] : 0;
        int s0 = v0, s1 = s0 + v1, s2 = s1 + v2, s3 = s2 + v3;
        int x = s3;
#pragma unroll
        for (int d = 1; d < 64; d <<= 1) {
            int t = __shfl_up(x, d, 64);
            if (lane >= d) x += t;
        }
        if (lane == 63) wsum[wid] = x;
        __syncthreads();
        if (wid == 0) {
            int s = (lane < 16) ? wsum[lane] : 0;
#pragma unroll
            for (int d = 1; d < 16; d <<= 1) {
                int t = __shfl_up(s, d, 64);
                if (lane >= d) s += t;
            }
            if (lane < 16) woff[lane] = s - wsum[lane];
            if (lane == 15) tot_s = s;
        }
        __syncthreads();
        int basev = carry_s + woff[wid] + (x - s3);
        if (i + 0 < n) off[i + 0] = basev;
        if (i + 1 < n) off[i + 1] = basev + s0;
        if (i + 2 < n) off[i + 2] = basev + s1;
        if (i + 3 < n) off[i + 3] = basev + s2;
        __syncthreads();
        if (tid == 0) carry_s += tot_s;
    }
    __syncthreads();
    if (tid == 0) off[n] = carry_s;
}

// ---------------- 3c. fill CSR src lists, both edge sets ----------------------------
__global__ __launch_bounds__(256) void fill_csr2(const int* __restrict__ eiA, const int* __restrict__ offA,
                                                 int* __restrict__ curA, int* __restrict__ srcsA,
                                                 const int* __restrict__ eiB, const int* __restrict__ offB,
                                                 int* __restrict__ curB, int* __restrict__ srcsB, int E) {
    int idx = blockIdx.x * 256 + threadIdx.x;
    int which = idx >= E;
    int e = idx - (which ? E : 0);
    if (e >= E) return;
    const int* ei = which ? eiB : eiA;
    const int* off = which ? offB : offA;
    int* cursor = which ? curB : curA;
    int* srcs = which ? srcsB : srcsA;
    int s = ei[e], d = ei[E + e];
    int slot = off[d] + atomicAdd(&cursor[d], 1);
    srcs[slot] = s;
}

// ---------------- 4. gather: one wave per dst node; 2-edge unroll -------------------
__global__ __launch_bounds__(256) void edge_gather2(const int* __restrict__ offA, const int* __restrict__ srcsA,
                                                    const float* __restrict__ asA, const float* __restrict__ adA,
                                                    const u16* __restrict__ hA, u16* __restrict__ outA,
                                                    const int* __restrict__ offB, const int* __restrict__ srcsB,
                                                    const float* __restrict__ asB, const float* __restrict__ adB,
                                                    const u16* __restrict__ hB, u16* __restrict__ outB, int N) {
    int gid = blockIdx.x * 256 + threadIdx.x;
    int dall = gid >> 6;
    int which = dall >= N;
    int d = dall - (which ? N : 0);
    if (d >= N) return;
    const int* off = which ? offB : offA;
    const int* srcs = which ? srcsB : srcsA;
    const float* a_src = which ? asB : asA;
    const float* a_dst = which ? adB : adA;
    const u16* h = which ? hB : hA;
    u16* out = which ? outB : outA;
    int lane = gid & 63;
    int hh = lane >> 5;
    int f = lane * 4;
    float ad0 = a_dst[d * 2 + hh];
    int beg = off[d], end = off[d + 1];
    float4 acc = {0.f, 0.f, 0.f, 0.f};
    float S = 0.f;
    int p = beg;
    for (; p + 2 <= end; p += 2) {       // two independent gather chains in flight
        int s0 = srcs[p], s1 = srcs[p + 1];
        ushort4 x0 = *(const ushort4*)(h + (size_t)s0 * 256 + f);
        ushort4 x1 = *(const ushort4*)(h + (size_t)s1 * 256 + f);
        float v0 = a_src[s0 * 2 + hh] + ad0;
        float v1 = a_src[s1 * 2 + hh] + ad0;
        v0 = v0 > 0.f ? v0 : 0.2f * v0;
        v1 = v1 > 0.f ? v1 : 0.2f * v1;
        float e0 = __expf(v0), e1 = __expf(v1);
        S += e0 + e1;
        acc.x += e0 * bf2f(x0.x) + e1 * bf2f(x1.x);
        acc.y += e0 * bf2f(x0.y) + e1 * bf2f(x1.y);
        acc.z += e0 * bf2f(x0.z) + e1 * bf2f(x1.z);
        acc.w += e0 * bf2f(x0.w) + e1 * bf2f(x1.w);
    }
    if (p < end) {
        int s0 = srcs[p];
        ushort4 x0 = *(const ushort4*)(h + (size_t)s0 * 256 + f);
        float v0 = a_src[s0 * 2 + hh] + ad0;
        v0 = v0 > 0.f ? v0 : 0.2f * v0;
        float e0 = __expf(v0);
        S += e0;
        acc.x += e0 * bf2f(x0.x);
        acc.y += e0 * bf2f(x0.y);
        acc.z += e0 * bf2f(x0.z);
        acc.w += e0 * bf2f(x0.w);
    }
    float inv = 1.f / (S + 1e-16f);
    ushort4 o = {f2bf(acc.x * inv), f2bf(acc.y * inv), f2bf(acc.z * inv), f2bf(acc.w * inv)};
    *(ushort4*)(out + (size_t)d * 256 + f) = o;
}

// ---------------- 5. semantic scores; A bf16, kW pre-converted bf16 -----------------
#define SK 264
__global__ __launch_bounds__(256) void kgemm_score2(const u16* __restrict__ outA,
                                                    const u16* __restrict__ outB,
                                                    const u16* __restrict__ kwb,
                                                    const float* __restrict__ kb,
                                                    const float* __restrict__ qv,
                                                    float* __restrict__ score) {
    __shared__ u16 Bs[128 * SK];          // 66 KB
    __shared__ float red[4];
    int slot = blockIdx.x >> 8;           // 0..1
    int b = blockIdx.x & 255;
    const u16* outm = slot ? outB : outA;
    int bn = b & 1;
    int bidx = b >> 1;                    // 0..127
    int tid = threadIdx.x;
    int w = tid >> 6, lane = tid & 63;
    int row16 = lane & 15, quad = lane >> 4;

#pragma unroll
    for (int i = 0; i < 16; ++i) {
        int c = tid + 256 * i;
        int r = c >> 5, col8 = (c & 31) * 8;
        *(bf16x8*)(Bs + r * SK + col8) = *(const bf16x8*)(kwb + (size_t)(bn * 128 + r) * 256 + col8);
    }
    __syncthreads();

    float kb0 = kb[bn * 128 + w * 32 + row16];
    float qn0 = qv[bn * 128 + w * 32 + row16];
    float kb1 = kb[bn * 128 + w * 32 + 16 + row16];
    float qn1 = qv[bn * 128 + w * 32 + 16 + row16];
    const u16* b0 = Bs + (w * 32 + row16) * SK + quad * 8;
    const u16* b1 = Bs + (w * 32 + 16 + row16) * SK + quad * 8;

    union U { uint4 q; u16 s[8]; bf16x8 v; };
    float p = 0.f;
    for (int mt = bidx; mt < 1250; mt += 128) {
        const u16* arow = outm + (size_t)(mt * 16 + row16) * 256 + quad * 8;
        U a[8];
#pragma unroll
        for (int s8 = 0; s8 < 8; ++s8) a[s8].q = *(const uint4*)(arow + s8 * 32);
        f32x4 acc0 = {0.f,0.f,0.f,0.f}, acc1 = {0.f,0.f,0.f,0.f};
#pragma unroll
        for (int s8 = 0; s8 < 8; ++s8) {
#pragma unroll
            for (int j = 0; j < 8; ++j)       // relu in bf16 domain
                if (a[s8].s[j] & 0x8000u) a[s8].s[j] = 0;
            bf16x8 bf0 = *(const bf16x8*)(b0 + s8 * 32);
            bf16x8 bf1 = *(const bf16x8*)(b1 + s8 * 32);
            acc0 = __builtin_amdgcn_mfma_f32_16x16x32_bf16(a[s8].v, bf0, acc0, 0, 0, 0);
            acc1 = __builtin_amdgcn_mfma_f32_16x16x32_bf16(a[s8].v, bf1, acc1, 0, 0, 0);
        }
#pragma unroll
        for (int r = 0; r < 4; ++r) {
            p += qn0 * fast_tanh(acc0[r] + kb0);
            p += qn1 * fast_tanh(acc1[r] + kb1);
        }
    }
#pragma unroll
    for (int off = 32; off >= 1; off >>= 1) p += __shfl_down(p, off, 64);
    if (lane == 0) red[w] = p;
    __syncthreads();
    if (tid == 0) unsafeAtomicAdd(&score[slot], red[0] + red[1] + red[2] + red[3]);
}

// ---------------- 6. softmax over 2 metapath scores, blend, gather del_idx ----------
__global__ __launch_bounds__(256) void final_combine(const u16* __restrict__ out_ad,
                                                     const u16* __restrict__ out_dd,
                                                     const float* __restrict__ score,
                                                     const int* __restrict__ del_idx,
                                                     float* __restrict__ out) {
    int i = blockIdx.x;
    int f = threadIdx.x;
    int node = del_idx[i];
    float s0 = score[0] * (1.f / 20000.f);
    float s1 = score[1] * (1.f / 20000.f);
    float m = fmaxf(s0, s1);
    float e0 = __expf(s0 - m), e1 = __expf(s1 - m);
    float inv = 1.f / (e0 + e1);
    float a0 = e0 * inv, a1 = e1 * inv;
    float v0 = bf2f(out_ad[(size_t)node * 256 + f]); v0 = v0 > 0.f ? v0 : 0.f;
    float v1 = bf2f(out_dd[(size_t)node * 256 + f]); v1 = v1 > 0.f ? v1 : 0.f;
    out[(size_t)i * 256 + f] = a0 * v0 + a1 * v1;
}

extern "C" void kernel_launch(void* const* d_in, const int* in_sizes, int n_in,
                              void* d_out, int out_size, void* d_ws, size_t ws_size,
                              hipStream_t stream) {
    const float* x_add    = (const float*)d_in[0];
    const float* x_del    = (const float*)d_in[1];
    const float* W_add    = (const float*)d_in[2];
    const float* b_add    = (const float*)d_in[3];
    const float* W_del    = (const float*)d_in[4];
    const float* b_del    = (const float*)d_in[5];
    const float* att_ad_s = (const float*)d_in[6];
    const float* att_ad_d = (const float*)d_in[7];
    const float* att_dd_s = (const float*)d_in[12];
    const float* att_dd_d = (const float*)d_in[13];
    const float* k_W      = (const float*)d_in[14];
    const float* k_b      = (const float*)d_in[15];
    const float* q        = (const float*)d_in[16];
    const int* ei_ad      = (const int*)d_in[17];
    const int* ei_dd      = (const int*)d_in[20];
    const int* del_idx    = (const int*)d_in[21];
    float* out = (float*)d_out;

    const int N = 20000, E = 200000;
    char* ws = (char*)d_ws;
    size_t o = 0;
    // ---- zeroed region ----
    int* cnt_ad = (int*)(ws + o); o += (size_t)N * 4;
    int* cur_ad = (int*)(ws + o); o += (size_t)N * 4;
    int* cnt_dd = (int*)(ws + o); o += (size_t)N * 4;
    int* cur_dd = (int*)(ws + o); o += (size_t)N * 4;
    float* as_ad = (float*)(ws + o); o += (size_t)N * 2 * 4;
    float* ad_ad = (float*)(ws + o); o += (size_t)N * 2 * 4;
    float* as_dd = (float*)(ws + o); o += (size_t)N * 2 * 4;
    float* ad_dd = (float*)(ws + o); o += (size_t)N * 2 * 4;
    float* score = (float*)(ws + o); o += 256;
    size_t zero_bytes = o;
    // ---- written-once region ----
    u16* wb_add = (u16*)(ws + o); o += (size_t)256 * 768 * 2;
    u16* wb_del = (u16*)(ws + o); o += (size_t)256 * 768 * 2;
    u16* kwb    = (u16*)(ws + o); o += (size_t)256 * 256 * 2;
    int* off_ad = (int*)(ws + o); o += (size_t)(N + 1) * 4;
    int* off_dd = (int*)(ws + o); o += (size_t)(N + 1) * 4;
    int* srcs_ad = (int*)(ws + o); o += (size_t)E * 4;
    int* srcs_dd = (int*)(ws + o); o += (size_t)E * 4;
    u16* out_ad = (u16*)(ws + o); o += (size_t)N * 256 * 2;
    u16* out_dd = (u16*)(ws + o); o += (size_t)N * 256 * 2;
    u16* ha    = (u16*)(ws + o); o += (size_t)N * 256 * 2;
    u16* hd    = (u16*)(ws + o); o += (size_t)N * 256 * 2;

    hipMemsetAsync(d_ws, 0, zero_bytes, stream);

    // W/kW cvt + degree histogram, one dispatch
    prep_count<<<224 + (2 * E + 255) / 256, 256, 0, stream>>>(
        W_add, wb_add, W_del, wb_del, k_W, kwb, ei_ad, cnt_ad, ei_dd, cnt_dd, E);
    scan_two<<<2, 1024, 0, stream>>>(cnt_ad, off_ad, cnt_dd, off_dd, N);
    fill_csr2<<<(2 * E + 255) / 256, 256, 0, stream>>>(ei_ad, off_ad, cur_ad, srcs_ad,
                                                       ei_dd, off_dd, cur_dd, srcs_dd, E);

    // both projections (+ fused att-score dots): 1252 blocks
    gemm_h2<<<1252, 256, 0, stream>>>(x_add, wb_add, b_add, ha,
                                      x_del, wb_del, b_del, hd,
                                      att_ad_s, att_ad_d, att_dd_s, att_dd_d,
                                      as_ad, ad_ad, as_dd, ad_dd, N);

    edge_gather2<<<10000, 256, 0, stream>>>(off_ad, srcs_ad, as_ad, ad_ad, ha, out_ad,
                                            off_dd, srcs_dd, as_dd, ad_dd, hd, out_dd, N);

    kgemm_score2<<<512, 256, 0, stream>>>(out_ad, out_dd, kwb, k_b, q, score);
    final_combine<<<4096, 256, 0, stream>>>(out_ad, out_dd, score, del_idx, out);
}